// Round 19
// baseline (269.137 us; speedup 1.0000x reference)
//
#include <hip/hip_runtime.h>
#include <hip/hip_bf16.h>

#define VN     5023
#define NBATCH 1024
#define N3     15069        // V*3
#define NPAD   15168        // N3 padded to 192*79
#define KS     5            // K-steps of 32 (K=160: 0..149 betas, 150=template, rest 0)
#define NKG    20           // KS*4 (k-groups of 8)

typedef short bf16x8 __attribute__((ext_vector_type(8)));
typedef float f32x4  __attribute__((ext_vector_type(4)));

__device__ __forceinline__ short f2bf(float x) {
    __hip_bfloat16 h = __float2bfloat16(x);
    return *reinterpret_cast<short*>(&h);
}

// ---- K0: pack sdp (+ v_template at k=150) into bf16 B-panels sdpB[kg][n] (8 k each) ----
// my-k convention: element e of group kg=(ks*4+g) is k = ks*32 + g*8 + e.
__global__ void k0_bf(const float* __restrict__ sd, const float* __restrict__ vt,
                      bf16x8* __restrict__ sdpB) {
    int i = blockIdx.x * 256 + threadIdx.x;          // over NKG*NPAD
    if (i >= NKG * NPAD) return;
    int kg = i / NPAD, n = i - kg * NPAD;
    int kbase = (kg >> 2) * 32 + (kg & 3) * 8;
    bf16x8 out;
#pragma unroll
    for (int e = 0; e < 8; e++) {
        int k = kbase + e;
        float val = 0.f;
        if (n < N3) {
            if (k < 150)       val = sd[(size_t)n * 150 + k];
            else if (k == 150) val = vt[n];
        }
        out[e] = f2bf(val);
    }
    sdpB[i] = out;
}

// ---- K1: JS[j3c][l] = sum_v jr[j,v]*sd[(v3+c)*150+l]  (l=150 -> v_template), f32 path ----
__global__ void k1_js(const float* __restrict__ jr, const float* __restrict__ sd,
                      const float* __restrict__ vt, float* __restrict__ JS) {
    int j3c = blockIdx.x;              // 0..14
    int j = j3c / 3, c = j3c - 3 * j;
    int l = threadIdx.x;               // 192 threads, use l<152
    if (l >= 152) return;
    int v0 = blockIdx.y * 157, v1 = min(v0 + 157, VN);
    float acc = 0.0f;
    for (int v = v0; v < v1; ++v) {
        float w = jr[j * VN + v];
        float s = (l < 150) ? sd[(size_t)(v * 3 + c) * 150 + l]
                            : ((l == 150) ? vt[v * 3 + c] : 0.f);
        acc += w * s;
    }
    atomicAdd(&JS[j3c * 152 + l], acc);
}

// ---- rodrigues (matches reference eps semantics) ----
__device__ __forceinline__ void rodrigues3(float x, float y, float z, float* R) {
    float ax = x + 1e-8f, ay = y + 1e-8f, az = z + 1e-8f;
    float ang = sqrtf(ax * ax + ay * ay + az * az);
    float inv = 1.0f / ang;
    float ux = x * inv, uy = y * inv, uz = z * inv;
    float co = cosf(ang), si = sinf(ang), t1 = 1.0f - co;
    float K[9] = {0.f, -uz, uy,  uz, 0.f, -ux,  -uy, ux, 0.f};
    float K2[9];
#pragma unroll
    for (int r = 0; r < 3; r++)
#pragma unroll
        for (int cc = 0; cc < 3; cc++) {
            float a = 0.f;
#pragma unroll
            for (int k = 0; k < 3; k++) a += K[r * 3 + k] * K[k * 3 + cc];
            K2[r * 3 + cc] = a;
        }
#pragma unroll
    for (int i = 0; i < 9; i++) {
        float e = (i == 0 || i == 4 || i == 8) ? 1.f : 0.f;
        R[i] = e + si * K[i] + t1 * K2[i];
    }
}

// ---- K2: per-batch betas -> bf16 A-panels betasA[kg][b]; joints; chain; rel; pf9 ----
__global__ void k2_pose(const float* __restrict__ shp, const float* __restrict__ expr,
                        const float* __restrict__ pose, const float* __restrict__ JS,
                        bf16x8* __restrict__ betasA, float* __restrict__ pf9,
                        float* __restrict__ rel) {
    int b = blockIdx.x;
    int tt = threadIdx.x;
    __shared__ float sB[152];
    __shared__ float sJ[15];
    for (int l = tt; l < 152; l += 64) {
        float val = 0.0f;
        if (l < 100) val = shp[b * 100 + l];
        else if (l < 150) val = expr[b * 50 + (l - 100)];
        else if (l == 150) val = 1.0f;   // picks up v_template / Jt columns
        sB[l] = val;
    }
    __syncthreads();
    // A-panel write: same my-k convention as k0 (k = l; kg = (l>>5)*4 + ((l>>3)&3); e = l&7)
    for (int l = tt; l < 160; l += 64) {
        float val = (l < 152) ? sB[l] : 0.f;
        int kg = (l >> 5) * 4 + ((l >> 3) & 3);
        short* dst = (short*)betasA;
        dst[((size_t)kg * NBATCH + b) * 8 + (l & 7)] = f2bf(val);
    }
    if (tt < 15) {
        float acc = 0.0f;
        const float* row = JS + tt * 152;
        for (int l = 0; l < 152; ++l) acc += row[l] * sB[l];
        sJ[tt] = acc;
    }
    __syncthreads();
    if (tt == 0) {
        float p[6];
#pragma unroll
        for (int i = 0; i < 6; i++) p[i] = pose[b * 6 + i];
        float R0[9], RJ[9];
        rodrigues3(p[0], p[1], p[2], R0);
        rodrigues3(p[3], p[4], p[5], RJ);
        float Jm[5][3];
#pragma unroll
        for (int jj = 0; jj < 5; jj++)
#pragma unroll
            for (int cc = 0; cc < 3; cc++) Jm[jj][cc] = sJ[jj * 3 + cc];
        float rj[5][3];
#pragma unroll
        for (int cc = 0; cc < 3; cc++) {
            rj[0][cc] = Jm[0][cc];
            rj[1][cc] = Jm[1][cc] - Jm[0][cc];
            rj[2][cc] = Jm[2][cc] - Jm[1][cc];
            rj[3][cc] = Jm[3][cc] - Jm[1][cc];
            rj[4][cc] = Jm[4][cc] - Jm[1][cc];
        }
        float tw[5][3];
#pragma unroll
        for (int cc = 0; cc < 3; cc++) tw[0][cc] = rj[0][cc];
#pragma unroll
        for (int cc = 0; cc < 3; cc++)
            tw[1][cc] = R0[cc * 3 + 0] * rj[1][0] + R0[cc * 3 + 1] * rj[1][1] + R0[cc * 3 + 2] * rj[1][2] + tw[0][cc];
#pragma unroll
        for (int jj = 2; jj < 5; jj++)
#pragma unroll
            for (int cc = 0; cc < 3; cc++)
                tw[jj][cc] = R0[cc * 3 + 0] * rj[jj][0] + R0[cc * 3 + 1] * rj[jj][1] + R0[cc * 3 + 2] * rj[jj][2] + tw[1][cc];
        float R2w[9];
#pragma unroll
        for (int r = 0; r < 3; r++)
#pragma unroll
            for (int cc = 0; cc < 3; cc++) {
                float a = 0.f;
#pragma unroll
                for (int k = 0; k < 3; k++) a += R0[r * 3 + k] * RJ[k * 3 + cc];
                R2w[r * 3 + cc] = a;
            }
        float* ro = rel + b * 80;
#pragma unroll
        for (int jj = 0; jj < 5; jj++) {
            const float* Rw = (jj == 2) ? R2w : R0;
#pragma unroll
            for (int rr = 0; rr < 3; rr++) {
                ro[jj * 16 + rr * 4 + 0] = Rw[rr * 3 + 0];
                ro[jj * 16 + rr * 4 + 1] = Rw[rr * 3 + 1];
                ro[jj * 16 + rr * 4 + 2] = Rw[rr * 3 + 2];
                float tj = Rw[rr * 3 + 0] * Jm[jj][0] + Rw[rr * 3 + 1] * Jm[jj][1] + Rw[rr * 3 + 2] * Jm[jj][2];
                ro[jj * 16 + rr * 4 + 3] = tw[jj][rr] - tj;
            }
            ro[jj * 16 + 12] = 0.f; ro[jj * 16 + 13] = 0.f; ro[jj * 16 + 14] = 0.f; ro[jj * 16 + 15] = 1.f;
        }
        float* pf = pf9 + b * 12;
#pragma unroll
        for (int e = 0; e < 9; e++) pf[e] = RJ[e] - ((e == 0 || e == 4 || e == 8) ? 1.f : 0.f);
        pf[9] = 0.f; pf[10] = 0.f; pf[11] = 0.f;
    }
}

// ---- K3: MFMA blend-GEMM + LDS exchange + pose/LBS/T epilogue ----
// Block: 256 thr (4 waves) = 16 batches x 192 n (64 vertices).
// MFMA 16x16x32_bf16: A=betas (row=lane&15 -> batch), B=sdp (col=lane&15 -> n),
// D lane layout (HW-verified m89): col=lane&15, row=(lane>>4)*4+reg.
// A/B both packed with identical (group,elem)->k maps, so internal k-label cancels.
__global__ void __launch_bounds__(256, 2)
k3_mfma(const bf16x8* __restrict__ sdpB, const bf16x8* __restrict__ betasA,
        const float* __restrict__ pd, const float* __restrict__ lw,
        const float* __restrict__ pf9, const float* __restrict__ rel,
        float* __restrict__ outv, float* __restrict__ outT) {
    __shared__ float vsh[16][200];   // [batch][n_local], padded 192->200 (bank spread)

    int tid = threadIdx.x;
    int w = tid >> 6, l = tid & 63;
    int row16 = l & 15, g = l >> 4;
    int b0 = blockIdx.y * 16;
    int n0 = blockIdx.x * 192;

    // A-fragments: betas rows b0..b0+15, all 5 K-steps (reused across 3 n-tiles)
    bf16x8 afr[5];
#pragma unroll
    for (int ks = 0; ks < 5; ks++)
        afr[ks] = betasA[(size_t)(ks * 4 + g) * NBATCH + b0 + row16];

    f32x4 acc0 = {0.f, 0.f, 0.f, 0.f}, acc1 = acc0, acc2 = acc0;
    {
        int ntb = n0 + (w * 3) * 16 + row16;
#pragma unroll
        for (int ks = 0; ks < 5; ks++) {
            size_t base = (size_t)(ks * 4 + g) * NPAD;
            acc0 = __builtin_amdgcn_mfma_f32_16x16x32_bf16(afr[ks], sdpB[base + ntb],      acc0, 0, 0, 0);
            acc1 = __builtin_amdgcn_mfma_f32_16x16x32_bf16(afr[ks], sdpB[base + ntb + 16], acc1, 0, 0, 0);
            acc2 = __builtin_amdgcn_mfma_f32_16x16x32_bf16(afr[ks], sdpB[base + ntb + 32], acc2, 0, 0, 0);
        }
    }
    // scatter to LDS: vsh[batch_local][n_local]
    {
        int nl = (w * 3) * 16 + row16;
#pragma unroll
        for (int r = 0; r < 4; r++) {
            vsh[g * 4 + r][nl]      = acc0[r];
            vsh[g * 4 + r][nl + 16] = acc1[r];
            vsh[g * 4 + r][nl + 32] = acc2[r];
        }
    }

    // per-vertex epilogue inputs (independent of vsh; scheduled before barrier)
    int v_loc = tid & 63;
    int v = blockIdx.x * 64 + v_loc;
    bool vok = v < VN;
    int vc_ = vok ? v : VN - 1;
    float wj[5], pdv[9][3];
#pragma unroll
    for (int j = 0; j < 5; j++) wj[j] = lw[vc_ * 5 + j];
#pragma unroll
    for (int k = 0; k < 9; k++)
#pragma unroll
        for (int c = 0; c < 3; c++) pdv[k][c] = pd[(size_t)(9 + k) * N3 + vc_ * 3 + c];

    __syncthreads();

    // epilogue: wave w covers batches b0+4w..b0+4w+3, lane -> one vertex
#pragma unroll
    for (int i = 0; i < 4; i++) {
        int bl = w * 4 + i;
        int b = b0 + bl;
        const float* pf = pf9 + b * 12;   // wave-uniform
        const float* rb = rel + b * 80;   // wave-uniform
        float vp[3];
#pragma unroll
        for (int c = 0; c < 3; c++) {
            float x = vsh[bl][v_loc * 3 + c];         // v_shaped (template in col 150)
#pragma unroll
            for (int k = 0; k < 9; k++) x += pf[k] * pdv[k][c];
            vp[c] = x;
        }
        float T[16];
#pragma unroll
        for (int e = 0; e < 16; e++) T[e] = 0.0f;
#pragma unroll
        for (int j = 0; j < 5; j++) {
            float wgt = wj[j];
            const float4 r0 = *(const float4*)(rb + j * 16 + 0);
            const float4 r1 = *(const float4*)(rb + j * 16 + 4);
            const float4 r2 = *(const float4*)(rb + j * 16 + 8);
            const float4 r3 = *(const float4*)(rb + j * 16 + 12);
            T[0]  += wgt * r0.x;  T[1]  += wgt * r0.y;  T[2]  += wgt * r0.z;  T[3]  += wgt * r0.w;
            T[4]  += wgt * r1.x;  T[5]  += wgt * r1.y;  T[6]  += wgt * r1.z;  T[7]  += wgt * r1.w;
            T[8]  += wgt * r2.x;  T[9]  += wgt * r2.y;  T[10] += wgt * r2.z;  T[11] += wgt * r2.w;
            T[12] += wgt * r3.x;  T[13] += wgt * r3.y;  T[14] += wgt * r3.z;  T[15] += wgt * r3.w;
        }
        float vo[3];
#pragma unroll
        for (int rr = 0; rr < 3; rr++)
            vo[rr] = T[rr * 4 + 0] * vp[0] + T[rr * 4 + 1] * vp[1] + T[rr * 4 + 2] * vp[2] + T[rr * 4 + 3];

        if (vok) {
            size_t vbase = (size_t)b * VN + v;
            float* pv = outv + vbase * 3;
            pv[0] = vo[0]; pv[1] = vo[1]; pv[2] = vo[2];
            float4* pT = (float4*)(outT + vbase * 16);
            pT[0] = make_float4(T[0],  T[1],  T[2],  T[3]);
            pT[1] = make_float4(T[4],  T[5],  T[6],  T[7]);
            pT[2] = make_float4(T[8],  T[9],  T[10], T[11]);
            pT[3] = make_float4(T[12], T[13], T[14], T[15]);
        }
    }
}

// ---------------- launch ----------------
extern "C" void kernel_launch(void* const* d_in, const int* in_sizes, int n_in,
                              void* d_out, int out_size, void* d_ws, size_t ws_size,
                              hipStream_t stream) {
    const float* shp  = (const float*)d_in[0];  // [1024,100]
    const float* expr = (const float*)d_in[1];  // [1024,50]
    const float* pose = (const float*)d_in[2];  // [1024,6]
    const float* vt   = (const float*)d_in[3];  // [5023,3]
    const float* sd   = (const float*)d_in[4];  // [5023,3,150]
    const float* pd   = (const float*)d_in[5];  // [36,15069]
    const float* jr   = (const float*)d_in[6];  // [5,5023]
    const float* lw   = (const float*)d_in[7];  // [5023,5]

    float* outv = (float*)d_out;
    float* outT = outv + (size_t)NBATCH * VN * 3;

    char* w = (char*)d_ws;
    const size_t SDPB_B  = (size_t)NKG * NPAD * 16;         // 4,853,760
    const size_t BETA_B  = (size_t)NKG * NBATCH * 16;       // 327,680
    const size_t JS_B    = 15 * 152 * 4;                    // 9,120
    const size_t PF9_B   = (size_t)NBATCH * 12 * 4;         // 49,152
    bf16x8* sdpB   = (bf16x8*)w;
    bf16x8* betasA = (bf16x8*)(w + SDPB_B);
    float*  JS     = (float*)(w + SDPB_B + BETA_B);
    float*  pf9    = (float*)(w + SDPB_B + BETA_B + JS_B);
    float*  rel    = (float*)(w + SDPB_B + BETA_B + JS_B + PF9_B);

    hipMemsetAsync(JS, 0, JS_B, stream);
    k0_bf<<<(NKG * NPAD + 255) / 256, 256, 0, stream>>>(sd, vt, sdpB);
    k1_js<<<dim3(15, 32), 192, 0, stream>>>(jr, sd, vt, JS);
    k2_pose<<<NBATCH, 64, 0, stream>>>(shp, expr, pose, JS, betasA, pf9, rel);
    k3_mfma<<<dim3(NPAD / 192, NBATCH / 16), 256, 0, stream>>>(sdpB, betasA, pd, lw, pf9, rel, outv, outT);
}